// Round 13
// baseline (147.436 us; speedup 1.0000x reference)
//
#include <hip/hip_runtime.h>
#include <hip/hip_cooperative_groups.h>

#define N_  128
#define C_  256
#define T_  48
#define V_  25

namespace cg = cooperative_groups;
typedef float v4f __attribute__((ext_vector_type(4)));

// Cooperative single-dispatch, 3 phases over grid 512x512 (2 blocks/CU, all resident):
//  P1: row means - block o streams rows [o*3072, (o+1)*3072) via LDS, stride-25 reduce.
//  grid.sync()
//  P2: gate chain for (n = o>>2, quad = o&3) from xbar (R12-K2 prologue).
//  P3: apply - re-read x (should be L3-resident from P1) * gate -> NT float4 store.
// LDS is a 51.2 KB union: P1 uses all of it as a row-stage; P2/P3 carve arrays.
__global__ __launch_bounds__(512, 4) void k_coop(
    const float* __restrict__ x,
    const float* __restrict__ wsq, const float* __restrict__ bsq,
    const float* __restrict__ gamma, const float* __restrict__ beta,
    const float* __restrict__ rmean, const float* __restrict__ rvar,
    const float* __restrict__ wc1, const float* __restrict__ bc1,
    const float* __restrict__ wex, const float* __restrict__ bex,
    float* __restrict__ xbar, float* __restrict__ out)
{
    extern __shared__ float S[];          // 12800 floats = 51,200 B
    const int tid = threadIdx.x;
    const unsigned bid = blockIdx.x;
    const unsigned o   = (bid & 7u) * 64u + (bid >> 3);   // bijective XCD chunk swizzle

    // ================= Phase 1: row means (pure HBM read stream) =================
    {
        const v4f* x4 = (const v4f*)x;
        float* xs = S;                                     // 512 rows x 25 floats
        for (int ch = 0; ch < 6; ++ch) {
            const unsigned g4 = (o * 6u + ch) * 3200u;     // f4 base of 512-row chunk
            #pragma unroll
            for (int i = 0; i < 7; ++i) {
                int j = i * 512 + tid;
                if (j < 3200) ((v4f*)xs)[j] = x4[g4 + j];
            }
            __syncthreads();
            const float* row = xs + tid * 25;
            float s = 0.f;
            #pragma unroll
            for (int v = 0; v < 25; ++v) s += row[v];      // stride 25: conflict-free
            xbar[(o * 6u + ch) * 512u + tid] = s * 0.04f;
            __syncthreads();
        }
    }
    cg::this_grid().sync();

    // ================= Phase 2: gate chain for (n, quad) =================
    float* xm   = S;            // [t][c]    3072 floats
    float* wsqL = S + 3072;     // [c][r] stride 17, 4352 floats
    float* gs   = S + 7424;     // gate [c][t], 3072 floats
    float* part = S + 10496;    // 384
    float* ybn  = S + 10880;    // 192
    float* y1   = S + 11072;    // 192
    float* mv   = S + 11264;    // 192

    const unsigned n  = o >> 2;
    const unsigned qd = o & 3u;

    for (int j = tid; j < 3072; j += 512) {
        int c = j / 12, t = j - c * 12;
        xm[t * 256 + c] = xbar[(unsigned)((n * 256u + c) * 48u + qd * 12u + t)];
    }
    #pragma unroll
    for (int it = 0; it < 8; ++it) {
        int j = it * 512 + tid;
        int r = j >> 8, c = j & 255;
        wsqL[c * 17 + r] = wsq[j];
    }
    __syncthreads();

    if (tid < 384) {                       // B1: squeeze partials (t, r, half)
        int t = tid >> 5, rh = tid & 31, r = rh >> 1, h = rh & 1;
        float acc = 0.f;
        #pragma unroll 8
        for (int i = 0; i < 128; ++i)
            acc += xm[t * 256 + h * 128 + i] * wsqL[(h * 128 + i) * 17 + r];
        part[tid] = acc;
    }
    __syncthreads();
    if (tid < 192) {                       // B1b: combine + BN (bsq folded)
        int t = tid >> 4, r = tid & 15;
        float acc = part[t * 32 + r * 2] + part[t * 32 + r * 2 + 1];
        float sc = gamma[r] * rsqrtf(rvar[r] + 1e-5f);
        ybn[t * 16 + r] = (acc + bsq[r]) * sc + (beta[r] - rmean[r] * sc);
    }
    __syncthreads();
    if (tid < 192) {                       // B2: conv1
        int t = tid >> 4, s = tid & 15;
        float acc = bc1[s];
        #pragma unroll
        for (int r = 0; r < 16; ++r) acc += ybn[t * 16 + r] * wc1[s * 16 + r];
        y1[t * 16 + s] = acc;
    }
    __syncthreads();
    if (tid < 192) {                       // B3: temporal diff (quad = 4 whole segs)
        int t = tid >> 4, r = tid & 15;
        mv[tid] = ((t % 3) < 2) ? (y1[(t + 1) * 16 + r] - ybn[t * 16 + r]) : 0.f;
    }
    __syncthreads();
    {                                      // B4: expand + sigmoid (c, t-half)
        int c = tid & 255, half = tid >> 8;
        float wexr[16];
        #pragma unroll
        for (int r = 0; r < 16; ++r) wexr[r] = wex[c * 16 + r];
        float be = bex[c];
        #pragma unroll
        for (int t = half * 6; t < half * 6 + 6; ++t) {
            float a = be;
            #pragma unroll
            for (int r = 0; r < 16; ++r) a += mv[t * 16 + r] * wexr[r];
            gs[c * 12 + t] = 1.f / (1.f + expf(-a));
        }
    }
    __syncthreads();

    // ================= Phase 3: apply (L3 re-read + NT store) =================
    {
        const v4f* x4 = (const v4f*)x + (size_t)n * 76800u + qd * 75u;  // + c*300 + k
        v4f*       o4 = (v4f*)out     + (size_t)n * 76800u + qd * 75u;
        #pragma unroll 4
        for (int it = 0; it < 38; ++it) {
            int j = it * 512 + tid;
            if (j < 19200) {
                unsigned c = ((unsigned)j * 55926u) >> 22;   // j/75 (exact j<19200)
                int k = j - (int)c * 75;
                v4f v = x4[c * 300 + k];
                int m0  = k * 4;
                int t0  = (m0 * 41) >> 10;                   // m0/25 (exact m0<1024)
                int t3  = ((m0 + 3) * 41) >> 10;
                int rem = m0 - t0 * 25;
                float g0 = gs[c * 12 + t0];
                float g3 = gs[c * 12 + t3];
                v4f ov;
                ov.x = v.x * g0;
                ov.y = v.y * ((rem + 1 < 25) ? g0 : g3);
                ov.z = v.z * ((rem + 2 < 25) ? g0 : g3);
                ov.w = v.w * ((rem + 3 < 25) ? g0 : g3);
                __builtin_nontemporal_store(ov, &o4[c * 300 + k]);
            }
        }
    }
}

extern "C" void kernel_launch(void* const* d_in, const int* in_sizes, int n_in,
                              void* d_out, int out_size, void* d_ws, size_t ws_size,
                              hipStream_t stream) {
    const float* x     = (const float*)d_in[0];
    const float* wsq   = (const float*)d_in[1];
    const float* bsq   = (const float*)d_in[2];
    const float* gamma = (const float*)d_in[3];
    const float* beta  = (const float*)d_in[4];
    const float* rmean = (const float*)d_in[5];
    const float* rvar  = (const float*)d_in[6];
    const float* wc1   = (const float*)d_in[7];
    const float* bc1   = (const float*)d_in[8];
    const float* wex   = (const float*)d_in[9];
    const float* bex   = (const float*)d_in[10];
    float* xbar = (float*)d_ws;                    // N*C*T floats = 6.29 MB
    float* outp = (float*)d_out;

    void* args[] = { (void*)&x, (void*)&wsq, (void*)&bsq, (void*)&gamma,
                     (void*)&beta, (void*)&rmean, (void*)&rvar, (void*)&wc1,
                     (void*)&bc1, (void*)&wex, (void*)&bex,
                     (void*)&xbar, (void*)&outp };
    hipLaunchCooperativeKernel((const void*)k_coop, dim3(512), dim3(512),
                               args, 51200, stream);
}

// Round 14
// 102.829 us; speedup vs baseline: 1.4338x; 1.4338x over previous
//
#include <hip/hip_runtime.h>

#define N_  128
#define C_  256
#define T_  48
#define V_  25

typedef float v4f __attribute__((ext_vector_type(4)));

// ---- K1: row means. Pure HBM read stream; warms L3 with x. ----
__global__ __launch_bounds__(256) void k_rowmean(const float* __restrict__ x,
                                                 float* __restrict__ xbar) {
    __shared__ float xs[6400];
    const int tid = threadIdx.x;
    const v4f* x4 = (const v4f*)x;
    const unsigned base4 = blockIdx.x * 1600u;
    #pragma unroll
    for (int k = 0; k < 7; ++k) {
        int i4 = k * 256 + tid;
        if (i4 < 1600) ((v4f*)xs)[i4] = x4[base4 + i4];
    }
    __syncthreads();
    float s = 0.f;
    #pragma unroll
    for (int v = 0; v < 25; ++v) s += xs[tid * 25 + v];   // stride 25: conflict-free
    xbar[blockIdx.x * 256u + tid] = s * 0.04f;
}

// ---- K2: gate math. Block = (n, half of T). 256 blocks, ~8 us. ----
__global__ __launch_bounds__(256) void k_gate(const float* __restrict__ xbar,
    const float* __restrict__ wsq, const float* __restrict__ bsq,
    const float* __restrict__ gamma, const float* __restrict__ beta,
    const float* __restrict__ rmean, const float* __restrict__ rvar,
    const float* __restrict__ wc1, const float* __restrict__ bc1,
    const float* __restrict__ wex, const float* __restrict__ bex,
    float* __restrict__ gate) {
    __shared__ float xm[256 * 25];   // [c][k], stride 25
    __shared__ float ybn[384];       // [t][r]
    __shared__ float y1[384];        // [t][s]
    __shared__ float mv[384];        // [t][r]
    const int tid = threadIdx.x;
    const int n   = blockIdx.x >> 1;
    const int t0  = (blockIdx.x & 1) * 24;     // 24%3==0: segments don't cross halves
    for (int j = tid; j < 6144; j += 256) {
        int c = j / 24, k = j - c * 24;
        xm[c * 25 + k] = xbar[(unsigned)((n * 256 + c) * 48 + t0 + k)];
    }
    __syncthreads();
    for (int p = tid; p < 384; p += 256) {     // squeeze + BN
        int t = p >> 4, r = p & 15;
        float acc = 0.f;
        for (int c = 0; c < 256; ++c) acc += xm[c * 25 + t] * wsq[r * 256 + c];
        float sc = gamma[r] * rsqrtf(rvar[r] + 1e-5f);
        ybn[t * 16 + r] = (acc + bsq[r]) * sc + (beta[r] - rmean[r] * sc);
    }
    __syncthreads();
    for (int p = tid; p < 384; p += 256) {     // conv1
        int t = p >> 4, s = p & 15;
        float acc = bc1[s];
        #pragma unroll
        for (int r = 0; r < 16; ++r) acc += ybn[t * 16 + r] * wc1[s * 16 + r];
        y1[t * 16 + s] = acc;
    }
    __syncthreads();
    for (int p = tid; p < 384; p += 256) {     // temporal diff
        int t = p >> 4, r = p & 15;
        mv[p] = ((t % 3) < 2) ? (y1[(t + 1) * 16 + r] - ybn[t * 16 + r]) : 0.f;
    }
    __syncthreads();
    {                                          // expand + sigmoid: thread = c
        float wexr[16];
        #pragma unroll
        for (int r = 0; r < 16; ++r) wexr[r] = wex[tid * 16 + r];
        float be = bex[tid];
        float* gout = gate + (unsigned)((n * 256 + tid) * 48 + t0);
        #pragma unroll
        for (int t = 0; t < 24; ++t) {
            float a = be;
            #pragma unroll
            for (int r = 0; r < 16; ++r) a += mv[t * 16 + r] * wexr[r];
            gout[t] = 1.f / (1.f + expf(-a));
        }
    }
}

// ---- K3: apply. Grid-stride streamer, PLAIN stores (NT-store A/B test). ----
__global__ __launch_bounds__(256) void k_apply(const float* __restrict__ x,
                                               const float* __restrict__ gate,
                                               float* __restrict__ out) {
    const v4f* x4 = (const v4f*)x;
    v4f* o4 = (v4f*)out;
    const unsigned total4 = 9830400u;                 // N*C*T*V/4
    for (unsigned i4 = blockIdx.x * 256u + threadIdx.x; i4 < total4;
         i4 += 4096u * 256u) {
        v4f xv = x4[i4];
        unsigned i0 = i4 * 4u;
        unsigned r0 = i0 / 25u;                        // compiler magic-div
        unsigned j  = i0 - r0 * 25u;
        unsigned r3 = (j + 3u >= 25u) ? r0 + 1u : r0;
        float g0 = gate[r0];
        float g3 = gate[r3];
        v4f ov;
        ov.x = xv.x * g0;
        ov.y = xv.y * ((j + 1u < 25u) ? g0 : g3);
        ov.z = xv.z * ((j + 2u < 25u) ? g0 : g3);
        ov.w = xv.w * ((j + 3u < 25u) ? g0 : g3);
        o4[i4] = ov;                                   // plain store
    }
}

extern "C" void kernel_launch(void* const* d_in, const int* in_sizes, int n_in,
                              void* d_out, int out_size, void* d_ws, size_t ws_size,
                              hipStream_t stream) {
    const float* x     = (const float*)d_in[0];
    const float* wsq   = (const float*)d_in[1];
    const float* bsq   = (const float*)d_in[2];
    const float* gamma = (const float*)d_in[3];
    const float* beta  = (const float*)d_in[4];
    const float* rmean = (const float*)d_in[5];
    const float* rvar  = (const float*)d_in[6];
    const float* wc1   = (const float*)d_in[7];
    const float* bc1   = (const float*)d_in[8];
    const float* wex   = (const float*)d_in[9];
    const float* bex   = (const float*)d_in[10];

    float* xbar = (float*)d_ws;                       // N*C*T floats
    float* gate = xbar + (size_t)N_ * C_ * T_;

    k_rowmean<<<6144, 256, 0, stream>>>(x, xbar);
    k_gate<<<256, 256, 0, stream>>>(xbar, wsq, bsq, gamma, beta,
                                    rmean, rvar, wc1, bc1, wex, bex, gate);
    k_apply<<<4096, 256, 0, stream>>>(x, gate, (float*)d_out);
}